// Round 6
// baseline (145.148 us; speedup 1.0000x reference)
//
#include <hip/hip_runtime.h>

// Shapes fixed by the reference's setup_inputs
#define BS    64        // B*S = 4*16
#define DDIM  512       // attention dim (K)
#define NV    32000     // vocab
#define TD    18        // tree depth
#define INNER 31999     // V-1 internal nodes (N)

typedef __attribute__((ext_vector_type(8))) short short8;
typedef __attribute__((ext_vector_type(4))) float floatx4;

__device__ __forceinline__ float bf16_to_f32(unsigned short u) {
    union { unsigned int i; float f; } v; v.i = ((unsigned int)u) << 16; return v.f;
}
__device__ __forceinline__ unsigned short f32_to_bf16(float f) {
    union { float f; unsigned int i; } v; v.f = f;
    unsigned int r = v.i + 0x7FFFu + ((v.i >> 16) & 1u);   // RNE
    return (unsigned short)(r >> 16);
}
__device__ __forceinline__ short8 cvt8(float4 a, float4 b) {
    short8 s;
    s[0] = (short)f32_to_bf16(a.x); s[1] = (short)f32_to_bf16(a.y);
    s[2] = (short)f32_to_bf16(a.z); s[3] = (short)f32_to_bf16(a.w);
    s[4] = (short)f32_to_bf16(b.x); s[5] = (short)f32_to_bf16(b.y);
    s[6] = (short)f32_to_bf16(b.z); s[7] = (short)f32_to_bf16(b.w);
    return s;
}

// --------------------------------------------------------------------------
// prep_att: att fp32 -> bf16 (8192 float4). Tiny (32 blocks). Pre-converting
// A halves A-load bytes and leaves only the B cvt8 in the GEMM k-step.
// --------------------------------------------------------------------------
__global__ __launch_bounds__(256) void prep_att(
    const float4* __restrict__ att, ushort4* __restrict__ attb)
{
    int i = blockIdx.x * 256 + threadIdx.x;    // 0..8191
    float4 a = att[i];
    ushort4 r;
    r.x = f32_to_bf16(a.x); r.y = f32_to_bf16(a.y);
    r.z = f32_to_bf16(a.z); r.w = f32_to_bf16(a.w);
    attb[i] = r;
}

// --------------------------------------------------------------------------
// x[m][n] = att[m,:]·weight[n,:], bf16 MFMA 16x16x32.
// ROUND-5 POST-MORTEM (vmcnt is IN-ORDER): round-5 loaded A-fragments
// INSIDE the compute macro, i.e. after the next chunk's B-loads were
// issued. First A use then had to drain chunk c+1's B-loads too ->
// pipeline degenerated to near-serial. FIX: chunk prefetch is atomic —
// A-frags + B-frags for chunk c issue together in the prefetch slot, so a
// chunk-c consumer waits vmcnt(16) = exactly chunk c, never c+1.
// Two named A and B register buffers (~150 VGPR, 3 waves/SIMD, 12/CU);
// in-flight bytes/CU = 12 waves x 16 KB >> 15 KB BDP -> BW/L3-bound.
// 1000 blocks; wave = 16n x 32m (2 MFMA/k-step); msub duplication of the
// weight rows is same-block, L1-absorbed.
// Epilogue: lp = log sigmoid(x) = -softplus(-x); lm = lp - x; pack bf16
// pair into u32; store TRANSPOSED pairsT[n][m] (gather's bs-lane layout).
// C/D map (m89): col = lane&15, row = (lane>>4)*4 + reg.
// --------------------------------------------------------------------------
#define LOADCH(BB, AA, c)                                                    \
    {                                                                        \
        _Pragma("unroll")                                                    \
        for (int s = 0; s < 4; ++s) {                                        \
            BB[2*s]   = *(const float4*)(bbase + (c)*128 + s*32);            \
            BB[2*s+1] = *(const float4*)(bbase + (c)*128 + s*32 + 4);        \
            AA[2*s]   = *(const short8*)(a0 + (c)*128 + s*32);               \
            AA[2*s+1] = *(const short8*)(a1 + (c)*128 + s*32);               \
        }                                                                    \
    }
#define COMPCH(BB, AA)                                                       \
    {                                                                        \
        _Pragma("unroll")                                                    \
        for (int s = 0; s < 4; ++s) {                                        \
            short8 bfrag = cvt8(BB[2*s], BB[2*s+1]);                         \
            acc0 = __builtin_amdgcn_mfma_f32_16x16x32_bf16(AA[2*s],   bfrag, acc0, 0, 0, 0); \
            acc1 = __builtin_amdgcn_mfma_f32_16x16x32_bf16(AA[2*s+1], bfrag, acc1, 0, 0, 0); \
        }                                                                    \
    }

__global__ __launch_bounds__(256) void gemm_logsig(
    const unsigned short* __restrict__ attb,     // [64][512] bf16
    const float* __restrict__ weight,            // [INNER][512] fp32
    unsigned int* __restrict__ pairsT)           // [NV][64] u32 (lm<<16)|lp
{
    const int tid  = threadIdx.x;
    const int lane = tid & 63;
    const int wave = tid >> 6;                   // 0..3
    const int nsub = wave & 1;                   // 16-n group
    const int msub = wave >> 1;                  // 32-m group
    const int l15  = lane & 15;
    const int quad = lane >> 4;
    const int B0   = blockIdx.x * 32;            // grid 1000 -> n-range 32

    floatx4 acc0 = (floatx4){0.f, 0.f, 0.f, 0.f};
    floatx4 acc1 = (floatx4){0.f, 0.f, 0.f, 0.f};

    int brow = B0 + nsub * 16 + l15;
    if (brow > INNER - 1) brow = INNER - 1;      // clamp; stores guarded
    const float*          bbase = weight + (size_t)brow * DDIM + quad * 8;
    const unsigned short* a0    = attb + (size_t)(msub * 32 + l15) * DDIM + quad * 8;
    const unsigned short* a1    = a0 + 16 * DDIM;

    float4 bufA[8], bufB[8];                     // B-stage, 2 x 32 VGPR
    short8 afA[8], afB[8];                       // A-stage, 2 x 32 VGPR

    LOADCH(bufA, afA, 0);                        // chunk 0: 16 loads
    LOADCH(bufB, afB, 1);                        // chunk 1: 16 loads
    COMPCH(bufA, afA);                           // waits vmcnt(16) = chunk 0 only
    LOADCH(bufA, afA, 2);
    COMPCH(bufB, afB);                           // waits chunk 1 only
    LOADCH(bufB, afB, 3);
    COMPCH(bufA, afA);                           // waits chunk 2 only
    COMPCH(bufB, afB);                           // chunk 3

    const int n = B0 + nsub * 16 + l15;
    if (n < INNER) {
        unsigned int* dst = pairsT + ((size_t)n << 6) + msub * 32 + quad * 4;
        floatx4 accs[2] = {acc0, acc1};
#pragma unroll
        for (int mt = 0; mt < 2; ++mt) {
            unsigned int wds[4];
#pragma unroll
            for (int r = 0; r < 4; ++r) {
                // m = msub*32 + mt*16 + quad*4 + r  (row of C = bs index)
                float x = accs[mt][r];
                float lp = -(fmaxf(-x, 0.f) + __logf(1.f + __expf(-fabsf(x))));
                float lm = lp - x;
                wds[r] = (unsigned int)f32_to_bf16(lp)
                       | ((unsigned int)f32_to_bf16(lm) << 16);
            }
            uint4 wv; wv.x = wds[0]; wv.y = wds[1]; wv.z = wds[2]; wv.w = wds[3];
            *(uint4*)(dst + mt * 16) = wv;       // pairsT[n][msub*32+mt*16+quad*4..+3]
        }
    }
}

// --------------------------------------------------------------------------
// out[bs][v] = sum_t half(pairsT[e>>1][bs], e&1),  e = 2*idx[v*18+t]+signbit.
// LANE = bs (tree path identical for all 64 bs rows); pair gather is a
// fully coalesced 256-B read pairsT[n][0..63]. Per v-PAIR: read all 36
// e-values from LDS, issue all 36 gathers concurrently, then reduce —
// vmcnt drains progressively since consumption is oldest-load-first.
// Grid 1000 x 256 (32 v/block, 8 v/wave). Small LDS tile transposes
// per-lane sums so the out write is float4-coalesced along v.
// --------------------------------------------------------------------------
__global__ __launch_bounds__(256) void gather_bs(
    const unsigned int* __restrict__ pairsT,     // [NV][64] u32
    const int* __restrict__ idx,                 // int32/int64 [576000]
    const unsigned int* __restrict__ signbits,   // fp32 path_sign raw bits
    float* __restrict__ out)                     // [64][NV] fp32
{
    __shared__ unsigned int eLDS[576];           // e = 2*idx + signbit
    __shared__ float tile[32][65];               // +1 pad: conflict-free transpose
    const int tid   = threadIdx.x;
    const int lane  = tid & 63;                  // = bs
    const int wave  = tid >> 6;
    const int vbase = blockIdx.x * 32;

    // i64 iff first 8 odd u32 words are all zero (P_err ~ (1/32000)^8)
    const unsigned int* w = (const unsigned int*)idx;
    bool i64 = true;
#pragma unroll
    for (int j = 1; j < 16; j += 2) i64 &= (w[j] == 0u);

    for (int q = tid; q < 576; q += 256) {
        int g = vbase * TD + q;                  // max 575,999 — in bounds
        int val = i64 ? idx[2 * g] : idx[g];
        eLDS[q] = ((unsigned int)val << 1) | (signbits[g] >> 31);
    }
    __syncthreads();

#pragma unroll
    for (int i = 0; i < 8; i += 2) {
        const int vA = wave * 8 + i;
        const int vB = vA + 1;
        const unsigned int* cA = eLDS + vA * TD;
        const unsigned int* cB = eLDS + vB * TD;
        unsigned int eA[TD], eB[TD], pA[TD], pB[TD];
#pragma unroll
        for (int t = 0; t < TD; ++t) { eA[t] = cA[t]; eB[t] = cB[t]; }
#pragma unroll
        for (int t = 0; t < TD; ++t) {           // 36 loads, all independent
            pA[t] = pairsT[((size_t)(eA[t] >> 1) << 6) + lane];
            pB[t] = pairsT[((size_t)(eB[t] >> 1) << 6) + lane];
        }
        float sA = 0.f, sB = 0.f;
#pragma unroll
        for (int t = 0; t < TD; ++t) {
            sA += bf16_to_f32((unsigned short)(pA[t] >> ((eA[t] & 1u) << 4)));
            sB += bf16_to_f32((unsigned short)(pB[t] >> ((eB[t] & 1u) << 4)));
        }
        tile[vA][lane] = sA;
        tile[vB][lane] = sB;
    }
    __syncthreads();

    const int bs  = threadIdx.x >> 2;            // 0..63
    const int seg = threadIdx.x & 3;             // 0..3 (8 v each)
    float4 r0, r1;
    r0.x = tile[seg * 8 + 0][bs]; r0.y = tile[seg * 8 + 1][bs];
    r0.z = tile[seg * 8 + 2][bs]; r0.w = tile[seg * 8 + 3][bs];
    r1.x = tile[seg * 8 + 4][bs]; r1.y = tile[seg * 8 + 5][bs];
    r1.z = tile[seg * 8 + 6][bs]; r1.w = tile[seg * 8 + 7][bs];
    float4* dst = (float4*)(out + (size_t)bs * NV + vbase + seg * 8);
    dst[0] = r0; dst[1] = r1;
}

extern "C" void kernel_launch(void* const* d_in, const int* in_sizes, int n_in,
                              void* d_out, int out_size, void* d_ws, size_t ws_size,
                              hipStream_t stream)
{
    const float*        att    = (const float*)d_in[0];        // fp32 [4,16,512]
    const float*        weight = (const float*)d_in[1];        // fp32 [31999,512]
    const int*          pidx   = (const int*)d_in[2];          // int32/int64 [576000]
    const unsigned int* psign  = (const unsigned int*)d_in[3]; // fp32 bits [576000]
    // d_in[4] path_bias (redundant: bias=(1-sign)/2), d_in[5..6] scalars
    float* out = (float*)d_out;                                // fp32 [64][32000]

    // workspace: 8,257,536 B total (16B-aligned offsets)
    char* ws = (char*)d_ws;
    unsigned int* pairsT = (unsigned int*)ws;                  // 8,192,000 B
    ushort4*      attb   = (ushort4*)(ws + 8192000);           //    65,536 B

    prep_att<<<32, 256, 0, stream>>>((const float4*)att, attb);
    gemm_logsig<<<1000, 256, 0, stream>>>((const unsigned short*)attb, weight, pairsT);
    gather_bs<<<1000, 256, 0, stream>>>(pairsT, pidx, psign, out);
}